// Round 16
// baseline (95.994 us; speedup 1.0000x reference)
//
#include <hip/hip_runtime.h>
#include <hip/hip_bf16.h>

// x: [4, 4096, 4096] f32, W1: [48, 4096] f32, W2: [48, 48] f32
// out: [4, 4, 4096, 12] f32  (C, B, T, L/C)
#define DDIM 4096
#define LTOT 48

typedef __attribute__((ext_vector_type(4))) float f32x4;
typedef __attribute__((ext_vector_type(8))) short bf16x8;

__device__ __forceinline__ unsigned cvt_pk(float x, float y) {
    union { __hip_bfloat162 h; unsigned u; } c;
    c.h = __float22bfloat162_rn(make_float2(x, y));
    return c.u;
}

// ---- kernel 0: W1 fp32 -> bf16 (RNE) into workspace ----
__global__ void w1cvt_kernel(const float* __restrict__ w1, ushort* __restrict__ w1b) {
    int i = blockIdx.x * 256 + threadIdx.x;
    union { float f; unsigned u; } v; v.f = w1[i];
    unsigned r = v.u + 0x7fffu + ((v.u >> 16) & 1u);
    w1b[i] = (ushort)(r >> 16);
}

// ---- fused: 32-row / 256-thr blocks, 4-wave K-split, reg-staged DEPTH-3
// (SA/SB/SC cycle: chunks c+2 AND c+3 in flight -> 16KB/wave x 8 waves/CU
// = 128KB/CU = the probe's saturating regime). LDS = 8KB/wave bridge. ----
__global__ __launch_bounds__(256, 2) void fused_kernel(
        const float* __restrict__ x,
        const ushort* __restrict__ w1b,
        const float* __restrict__ w2,
        float* __restrict__ out) {
    // [0,32768): 4 waves x 8KB bridge; epilogue overlays after syncthreads.
    // [39936,40576): ssw[4][32] + scl[32]
    __shared__ __align__(1024) char smem[40576];

    const int tid  = threadIdx.x;
    const int wave = tid >> 6;    // K-quarter
    const int lane = tid & 63;
    const int rl   = lane & 15;   // A-row-in-tile / B-row / C-col / stage slot
    const int kg   = lane >> 4;   // k-group / stage row-in-group
    const int row0 = blockIdx.x * 32;
    const int kw   = wave * 1024;
    const int rot  = blockIdx.x & 15;

    char*  bridge = smem + wave * 8192;
    float* ssw    = (float*)(smem + 39936);   // [4][32]
    float* scl    = ssw + 128;                // [32]

    // bridge write: stage block j covers rows 4j+kg; lane's 16B slot sblk=rl
    // of row r lands at swizzled slot (rl ^ r) & 15
    int dwo[8];
    #pragma unroll
    for (int j = 0; j < 8; ++j) {
        int r = 4 * j + kg;
        dwo[j] = r * 256 + (((rl ^ r) & 15) << 4);
    }
    // bridge read: tile T row r=T*16+rl, logical block b=t*8+kg*2+p at b^rl
    int dro[2][2][2];
    #pragma unroll
    for (int T = 0; T < 2; ++T)
        #pragma unroll
        for (int t = 0; t < 2; ++t)
            #pragma unroll
            for (int p = 0; p < 2; ++p) {
                int r = T * 16 + rl;
                int b = t * 8 + kg * 2 + p;
                dro[T][t][p] = r * 256 + (((b ^ rl) & 15) << 4);
            }

    auto kcol = [&](int c) { return kw + ((c + rot) & 15) * 64; };

    // load chunk c (32 rows x 256B of this wave's K-window) into regs
    auto loadS = [&](int c, f32x4 (&S)[8]) {
        const float* base = x + (size_t)row0 * DDIM + kcol(c) + rl * 4;
        #pragma unroll
        for (int j = 0; j < 8; ++j)
            S[j] = *(const f32x4*)(base + (size_t)(4 * j + kg) * DDIM);
    };
    auto writeS = [&](f32x4 (&S)[8]) {
        #pragma unroll
        for (int j = 0; j < 8; ++j)
            *(f32x4*)(bridge + dwo[j]) = S[j];
    };

    float ss0 = 0.f, ss1 = 0.f;
    f32x4 acc0[3] = {{0.f,0.f,0.f,0.f},{0.f,0.f,0.f,0.f},{0.f,0.f,0.f,0.f}};
    f32x4 acc1[3] = {{0.f,0.f,0.f,0.f},{0.f,0.f,0.f,0.f},{0.f,0.f,0.f,0.f}};
    f32x4 SA[8], SB[8], SC[8];

    // prologue: chunks 0,1,2 -> regs; bridge <- chunk 0
    loadS(0, SA); loadS(1, SB); loadS(2, SC);
    writeS(SA);   // waits SA only; SB,SC stay in flight

    // body(c): bridge holds chunk c. The buffer that held chunk c (written to
    // bridge at end of body(c-1)) is dead -> load chunk c+3 into it (Sld).
    // Swr holds chunk c+1 (loaded in body(c-2), long complete) -> write it
    // to bridge after the frag reads (same-wave DS program order protects).
    auto body = [&](int c, f32x4 (&Sld)[8], f32x4 (&Swr)[8]) {
        f32x4 a[2][2][2];
        #pragma unroll
        for (int T = 0; T < 2; ++T)
            #pragma unroll
            for (int t = 0; t < 2; ++t)
                #pragma unroll
                for (int p = 0; p < 2; ++p)
                    a[T][t][p] = *(const f32x4*)(bridge + dro[T][t][p]);
        // B fragments (L2-hit; wait before MFMA is vmcnt(8), keeps c+3 in flight)
        bf16x8 Bf[2][3];
        #pragma unroll
        for (int t = 0; t < 2; ++t)
            #pragma unroll
            for (int n = 0; n < 3; ++n)
                Bf[t][n] = *(const bf16x8*)(w1b + (size_t)(n * 16 + rl) * DDIM
                                            + kcol(c) + t * 32 + kg * 8);
        if (c < 13) loadS(c + 3, Sld);
        #pragma unroll
        for (int t = 0; t < 2; ++t) {
            f32x4 a0 = a[0][t][0], a1 = a[0][t][1];
            f32x4 c0 = a[1][t][0], c1 = a[1][t][1];
            ss0 = fmaf(a0.x, a0.x, ss0); ss0 = fmaf(a0.y, a0.y, ss0);
            ss0 = fmaf(a0.z, a0.z, ss0); ss0 = fmaf(a0.w, a0.w, ss0);
            ss0 = fmaf(a1.x, a1.x, ss0); ss0 = fmaf(a1.y, a1.y, ss0);
            ss0 = fmaf(a1.z, a1.z, ss0); ss0 = fmaf(a1.w, a1.w, ss0);
            ss1 = fmaf(c0.x, c0.x, ss1); ss1 = fmaf(c0.y, c0.y, ss1);
            ss1 = fmaf(c0.z, c0.z, ss1); ss1 = fmaf(c0.w, c0.w, ss1);
            ss1 = fmaf(c1.x, c1.x, ss1); ss1 = fmaf(c1.y, c1.y, ss1);
            ss1 = fmaf(c1.z, c1.z, ss1); ss1 = fmaf(c1.w, c1.w, ss1);
            union { bf16x8 v; unsigned u[4]; } af, ag;
            af.u[0] = cvt_pk(a0.x, a0.y); af.u[1] = cvt_pk(a0.z, a0.w);
            af.u[2] = cvt_pk(a1.x, a1.y); af.u[3] = cvt_pk(a1.z, a1.w);
            ag.u[0] = cvt_pk(c0.x, c0.y); ag.u[1] = cvt_pk(c0.z, c0.w);
            ag.u[2] = cvt_pk(c1.x, c1.y); ag.u[3] = cvt_pk(c1.z, c1.w);
            #pragma unroll
            for (int n = 0; n < 3; ++n) {
                acc0[n] = __builtin_amdgcn_mfma_f32_16x16x32_bf16(
                              af.v, Bf[t][n], acc0[n], 0, 0, 0);
                acc1[n] = __builtin_amdgcn_mfma_f32_16x16x32_bf16(
                              ag.v, Bf[t][n], acc1[n], 0, 0, 0);
            }
        }
        if (c < 15) writeS(Swr);
    };

    // buffers cycle with period 3: body(c): Sld=buf[c%3], Swr=buf[(c+1)%3]
    for (int sp = 0; sp < 5; ++sp) {
        body(3 * sp,     SA, SB);
        body(3 * sp + 1, SB, SC);
        body(3 * sp + 2, SC, SA);
    }
    body(15, SA, SB);

    // ---- reductions & epilogue (R10/R15-verified, 256-thread) ----
    ss0 += __shfl_xor(ss0, 16); ss0 += __shfl_xor(ss0, 32);
    ss1 += __shfl_xor(ss1, 16); ss1 += __shfl_xor(ss1, 32);
    if (lane < 16) { ssw[wave * 32 + lane] = ss0; ssw[wave * 32 + 16 + lane] = ss1; }
    __syncthreads();   // all bridge reads done -> overlay LDS

    float* dots = (float*)smem;             // [4][32][48] = 24576 B
    float* gbuf = (float*)(smem + 24576);   // [32][48]    =  6144 B
    float* w2s  = (float*)(smem + 30720);   // [48][48]    =  9216 B

    #pragma unroll
    for (int n = 0; n < 3; ++n)
        #pragma unroll
        for (int i = 0; i < 4; ++i) {
            dots[(wave * 32 + kg * 4 + i) * 48 + n * 16 + rl]      = acc0[n][i];
            dots[(wave * 32 + 16 + kg * 4 + i) * 48 + n * 16 + rl] = acc1[n][i];
        }
    for (int i = tid; i < LTOT * LTOT; i += 256) w2s[i] = w2[i];
    if (tid < 32) {
        float st = ssw[tid] + ssw[32 + tid] + ssw[64 + tid] + ssw[96 + tid];
        scl[tid] = rsqrtf(st * (1.0f / (float)DDIM) + 1e-5f);
    }
    __syncthreads();

    #pragma unroll
    for (int i = 0; i < 6; ++i) {
        int v = tid + i * 256;                 // 0..1535 = 32*48
        int row = v / 48, col = v - row * 48;
        float d = dots[row * 48 + col]        + dots[(32 + row) * 48 + col]
                + dots[(64 + row) * 48 + col] + dots[(96 + row) * 48 + col];
        float h = d * scl[row];
        gbuf[row * 48 + col] = h * 0.5f * (1.0f + erff(h * 0.70710678118654752f));
    }
    __syncthreads();

    #pragma unroll
    for (int i = 0; i < 6; ++i) {
        int v = tid + i * 256;
        int row = v / 48, l = v - row * 48;
        float sacc = 0.f;
        #pragma unroll
        for (int k = 0; k < LTOT; ++k)
            sacc = fmaf(gbuf[row * 48 + k], w2s[l * LTOT + k], sacc);
        int rg = row0 + row;
        int b  = rg >> 12;
        int t  = rg & 4095;
        int c  = l / 12, j = l - c * 12;
        out[(((size_t)(c * 4 + b) * 4096 + t) * 12) + j] = sacc;
    }
}

extern "C" void kernel_launch(void* const* d_in, const int* in_sizes, int n_in,
                              void* d_out, int out_size, void* d_ws, size_t ws_size,
                              hipStream_t stream) {
    const float* x  = (const float*)d_in[0];
    const float* W1 = (const float*)d_in[1];
    const float* W2 = (const float*)d_in[2];
    float* out = (float*)d_out;
    ushort* w1b = (ushort*)d_ws;

    w1cvt_kernel<<<(LTOT * DDIM) / 256, 256, 0, stream>>>(W1, w1b);
    fused_kernel<<<16384 / 32, 256, 0, stream>>>(x, w1b, W2, out);
}

// Round 17
// 75.942 us; speedup vs baseline: 1.2640x; 1.2640x over previous
//
#include <hip/hip_runtime.h>
#include <hip/hip_bf16.h>

// x: [4, 4096, 4096] f32, W1: [48, 4096] f32, W2: [48, 48] f32
// out: [4, 4, 4096, 12] f32  (C, B, T, L/C)
#define DDIM 4096
#define LTOT 48

typedef __attribute__((ext_vector_type(4))) float f32x4;
typedef __attribute__((ext_vector_type(8))) short bf16x8;

__device__ __forceinline__ void gload_lds16(const void* g, void* l) {
    __builtin_amdgcn_global_load_lds(
        (const __attribute__((address_space(1))) void*)g,
        (__attribute__((address_space(3))) void*)l, 16, 0, 0);
}

__device__ __forceinline__ unsigned cvt_pk(float x, float y) {
    union { __hip_bfloat162 h; unsigned u; } c;
    c.h = __float22bfloat162_rn(make_float2(x, y));
    return c.u;
}

// ---- kernel 0: W1 fp32 -> bf16 (RNE) into workspace ----
__global__ void w1cvt_kernel(const float* __restrict__ w1, ushort* __restrict__ w1b) {
    int i = blockIdx.x * 256 + threadIdx.x;
    union { float f; unsigned u; } v; v.f = w1[i];
    unsigned r = v.u + 0x7fffu + ((v.u >> 16) & 1u);
    w1b[i] = (ushort)(r >> 16);
}

// ---- fused: 512-thr / 32-row blocks, wave=(m,k4); LDS-DMA staging DEPTH-4
// (4 buffers x 4KB per wave = 128KB/block, 1 block/CU, 8 waves/CU;
// in-flight = 3 stages x 4KB x 8 waves = 96KB/CU) + B reg-prefetch 4-deep
// (96 VGPR; hand-counted vmcnt(30) retires exactly [B(c):6][st(c):4]). ----
__global__ __launch_bounds__(512, 2) void fused_kernel(
        const float* __restrict__ x,
        const ushort* __restrict__ w1b,
        const float* __restrict__ w2,
        float* __restrict__ out) {
    // [0,131072): 8 waves x 4 buffers x 4096B staging (epilogue overlays)
    // [131072,131712): ssw[4][32] + scl[32]
    __shared__ __align__(1024) char smem[131712];

    const int tid  = threadIdx.x;
    const int wave = tid >> 6;
    const int lane = tid & 63;
    const int rl   = lane & 15;   // A-row-in-tile / B-row / C-col
    const int kg   = lane >> 4;   // k-group 0..3
    const int m    = wave & 1;    // row-half of block
    const int k4   = wave >> 1;   // K-quarter
    const int row0 = blockIdx.x * 32;
    const int wrow = m * 16;
    const int kw   = k4 * 1024;
    const int rot  = blockIdx.x & 15;

    char*  wbase = smem + wave * 16384;      // 4 x 4KB buffers
    float* ssw   = (float*)(smem + 131072);  // [4][32]
    float* scl   = ssw + 128;                // [32]

    // ds_read offsets: global 16B-block g of row rl stored at LDS slot g^rl
    int dso[2][2];
    #pragma unroll
    for (int h = 0; h < 2; ++h)
        #pragma unroll
        for (int p = 0; p < 2; ++p)
            dso[h][p] = rl * 256 + (((h * 8 + kg * 2 + p) ^ rl) << 4);

    // stage pipeline-step t into buffer t&3: 4 x 1KB DMA, linear LDS dest,
    // inverse-swizzled per-lane global source (R13-verified)
    auto stage = [&](int t) {
        const int kb = kw + ((t + rot) & 15) * 64;
        char* lb = wbase + (t & 3) * 4096;
        #pragma unroll
        for (int i = 0; i < 4; ++i) {
            int rloc = i * 4 + kg;
            int blkg = rl ^ rloc;
            const float* src = x + (size_t)(row0 + wrow + rloc) * DDIM + kb + blkg * 4;
            gload_lds16(src, lb + i * 1024);
        }
    };

    // B fragments for step s (6 x 16B); m-pair waves issue identical loads
    auto loadB = [&](int s, bf16x8 (&bl)[6]) {
        const ushort* bp = w1b + (size_t)rl * DDIM + kw + ((s + rot) & 15) * 64 + kg * 8;
        #pragma unroll
        for (int n = 0; n < 3; ++n)
            #pragma unroll
            for (int h = 0; h < 2; ++h)
                bl[n * 2 + h] = *(const bf16x8*)(bp + n * 16 * DDIM + h * 32);
    };

    float ss = 0.f;
    f32x4 acc[3] = {{0.f,0.f,0.f,0.f},{0.f,0.f,0.f,0.f},{0.f,0.f,0.f,0.f}};
    bf16x8 B0[6], B1[6], B2[6], B3[6];

    // prologue: [B(t):6][st(t):4] for t=0..3, order pinned -> 40 outstanding
    loadB(0, B0); __builtin_amdgcn_sched_barrier(0); stage(0);
    __builtin_amdgcn_sched_barrier(0);
    loadB(1, B1); __builtin_amdgcn_sched_barrier(0); stage(1);
    __builtin_amdgcn_sched_barrier(0);
    loadB(2, B2); __builtin_amdgcn_sched_barrier(0); stage(2);
    __builtin_amdgcn_sched_barrier(0);
    loadB(3, B3); __builtin_amdgcn_sched_barrier(0); stage(3);
    __builtin_amdgcn_sched_barrier(0);

    // body(c): wait retires exactly [B(c):6][st(c):4] (3 stages + 3 B stay in
    // flight). Consume Bu via SSA copy, refill same slot with B(c+4), then
    // issue stage(c+4) into the just-freed buffer (after lgkmcnt(0)).
    auto body = [&](int c, bf16x8 (&Bu)[6]) {
        if (c == 15)      asm volatile("s_waitcnt vmcnt(0)"  ::: "memory");
        else if (c == 14) asm volatile("s_waitcnt vmcnt(10)" ::: "memory");
        else if (c == 13) asm volatile("s_waitcnt vmcnt(20)" ::: "memory");
        else              asm volatile("s_waitcnt vmcnt(30)" ::: "memory");

        char* lb = wbase + (c & 3) * 4096;
        f32x4 a[2][2];
        #pragma unroll
        for (int h = 0; h < 2; ++h)
            #pragma unroll
            for (int p = 0; p < 2; ++p)
                a[h][p] = *(const f32x4*)(lb + dso[h][p]);

        bf16x8 Bt[6];   // SSA snapshot of B(c) (free renaming, no movs)
        #pragma unroll
        for (int i = 0; i < 6; ++i) Bt[i] = Bu[i];

        // frag reads done -> buffer c&3 free for stage(c+4)
        asm volatile("s_waitcnt lgkmcnt(0)" ::: "memory");
        __builtin_amdgcn_sched_barrier(0);
        if (c + 4 <= 15) loadB(c + 4, Bu);     // appended BEFORE the stage
        __builtin_amdgcn_sched_barrier(0);
        if (c + 4 <= 15) stage(c + 4);
        __builtin_amdgcn_sched_barrier(0);

        #pragma unroll
        for (int h = 0; h < 2; ++h) {
            f32x4 a0 = a[h][0], a1 = a[h][1];
            ss = fmaf(a0.x, a0.x, ss); ss = fmaf(a0.y, a0.y, ss);
            ss = fmaf(a0.z, a0.z, ss); ss = fmaf(a0.w, a0.w, ss);
            ss = fmaf(a1.x, a1.x, ss); ss = fmaf(a1.y, a1.y, ss);
            ss = fmaf(a1.z, a1.z, ss); ss = fmaf(a1.w, a1.w, ss);
            union { bf16x8 v; unsigned u[4]; } af;
            af.u[0] = cvt_pk(a0.x, a0.y); af.u[1] = cvt_pk(a0.z, a0.w);
            af.u[2] = cvt_pk(a1.x, a1.y); af.u[3] = cvt_pk(a1.z, a1.w);
            #pragma unroll
            for (int n = 0; n < 3; ++n)
                acc[n] = __builtin_amdgcn_mfma_f32_16x16x32_bf16(
                             af.v, Bt[n * 2 + h], acc[n], 0, 0, 0);
        }
    };

    for (int sp = 0; sp < 4; ++sp) {
        body(4 * sp + 0, B0);
        body(4 * sp + 1, B1);
        body(4 * sp + 2, B2);
        body(4 * sp + 3, B3);
    }

    // ---- reductions & epilogue (R13-verified, 512-thread) ----
    ss += __shfl_xor(ss, 16);
    ss += __shfl_xor(ss, 32);
    if (lane < 16) ssw[k4 * 32 + wrow + lane] = ss;
    __syncthreads();   // all staging reads done -> overlay LDS

    float* dots = (float*)smem;             // [4][32][48] = 24576 B
    float* gbuf = (float*)(smem + 24576);   // [32][48]    =  6144 B
    float* w2s  = (float*)(smem + 30720);   // [48][48]    =  9216 B

    #pragma unroll
    for (int n = 0; n < 3; ++n)
        #pragma unroll
        for (int i = 0; i < 4; ++i)
            dots[(k4 * 32 + wrow + kg * 4 + i) * 48 + n * 16 + rl] = acc[n][i];
    for (int i = tid; i < LTOT * LTOT; i += 512) w2s[i] = w2[i];
    if (tid < 32) {
        float st = ssw[tid] + ssw[32 + tid] + ssw[64 + tid] + ssw[96 + tid];
        scl[tid] = rsqrtf(st * (1.0f / (float)DDIM) + 1e-5f);
    }
    __syncthreads();

    #pragma unroll
    for (int i = 0; i < 3; ++i) {
        int v = tid + i * 512;                 // 0..1535 = 32*48
        int row = v / 48, col = v - row * 48;
        float d = dots[row * 48 + col]        + dots[(32 + row) * 48 + col]
                + dots[(64 + row) * 48 + col] + dots[(96 + row) * 48 + col];
        float h = d * scl[row];
        gbuf[row * 48 + col] = h * 0.5f * (1.0f + erff(h * 0.70710678118654752f));
    }
    __syncthreads();

    #pragma unroll
    for (int i = 0; i < 3; ++i) {
        int v = tid + i * 512;
        int row = v / 48, l = v - row * 48;
        float sacc = 0.f;
        #pragma unroll
        for (int k = 0; k < LTOT; ++k)
            sacc = fmaf(gbuf[row * 48 + k], w2s[l * LTOT + k], sacc);
        int rg = row0 + row;
        int b  = rg >> 12;
        int t  = rg & 4095;
        int c  = l / 12, j = l - c * 12;
        out[(((size_t)(c * 4 + b) * 4096 + t) * 12) + j] = sacc;
    }
}

extern "C" void kernel_launch(void* const* d_in, const int* in_sizes, int n_in,
                              void* d_out, int out_size, void* d_ws, size_t ws_size,
                              hipStream_t stream) {
    const float* x  = (const float*)d_in[0];
    const float* W1 = (const float*)d_in[1];
    const float* W2 = (const float*)d_in[2];
    float* out = (float*)d_out;
    ushort* w1b = (ushort*)d_ws;

    w1cvt_kernel<<<(LTOT * DDIM) / 256, 256, 0, stream>>>(W1, w1b);
    fused_kernel<<<16384 / 32, 512, 0, stream>>>(x, w1b, W2, out);
}

// Round 18
// 57.631 us; speedup vs baseline: 1.6657x; 1.3177x over previous
//
#include <hip/hip_runtime.h>
#include <hip/hip_bf16.h>

// x: [4, 4096, 4096] f32, W1: [48, 4096] f32, W2: [48, 48] f32
// out: [4, 4, 4096, 12] f32  (C, B, T, L/C)
// Session-best structure (round 10, 58.5 us):
//   32-row blocks, 4-wave K-split, global_load_lds double-buffered staging,
//   XOR-swizzled LDS, counted-vmcnt pipeline, fused RMS+GELU+W2 epilogue.
#define DDIM 4096
#define LTOT 48

typedef __attribute__((ext_vector_type(4))) float f32x4;
typedef __attribute__((ext_vector_type(8))) short bf16x8;

__device__ __forceinline__ void gload_lds16(const void* g, void* l) {
    __builtin_amdgcn_global_load_lds(
        (const __attribute__((address_space(1))) void*)g,
        (__attribute__((address_space(3))) void*)l, 16, 0, 0);
}

__device__ __forceinline__ unsigned cvt_pk(float x, float y) {
    union { __hip_bfloat162 h; unsigned u; } c;
    c.h = __float22bfloat162_rn(make_float2(x, y));
    return c.u;
}

// ---- kernel 0: W1 fp32 -> bf16 (RNE) into workspace ----
__global__ void w1cvt_kernel(const float* __restrict__ w1, ushort* __restrict__ w1b) {
    int i = blockIdx.x * 256 + threadIdx.x;
    union { float f; unsigned u; } v; v.f = w1[i];
    unsigned r = v.u + 0x7fffu + ((v.u >> 16) & 1u);
    w1b[i] = (ushort)(r >> 16);
}

// ---- fused: 32-row blocks (2 MFMA row-tiles/wave), 4-wave K-split,
//      DMA-staged double buffer (round-10 verbatim, session best) ----
__global__ __launch_bounds__(256, 2) void fused_kernel(
        const float* __restrict__ x,
        const ushort* __restrict__ w1b,
        const float* __restrict__ w2,
        float* __restrict__ out) {
    // staging: 4 waves x 2 buffers x 8192B (32 rows x 64 f32, XOR-swizzled)
    __shared__ __align__(1024) char smem[65536];
    __shared__ float ssw[4][32];
    __shared__ float scl[32];

    const int tid  = threadIdx.x;
    const int wave = tid >> 6;
    const int lane = tid & 63;
    const int rl   = lane & 15;   // A-row (within tile) / B-row / C-col
    const int kg   = lane >> 4;   // k-group 0..3
    const int row0 = blockIdx.x * 32;
    const int kw   = wave * 1024; // per-wave K range
    const int rot  = blockIdx.x & 15;

    char* wbase = smem + wave * 16384;

    // ds_read offsets for (tile T, half h, piece p): row r = T*16+rl,
    // logical 16B-block g = h*8+kg*2+p stored at LDS pos g ^ rl of row r
    int dso[2][2][2];
    #pragma unroll
    for (int T = 0; T < 2; ++T)
        #pragma unroll
        for (int h = 0; h < 2; ++h)
            #pragma unroll
            for (int p = 0; p < 2; ++p)
                dso[T][h][p] = (T * 16 + rl) * 256 + (((h * 8 + kg * 2 + p) ^ rl) << 4);

    // stage pipeline-step t into buffer t&1: 8 x 1KB DMA (rows i*4+kg),
    // linear LDS dest, inverse-swizzled per-lane global source
    auto stage = [&](int t) {
        const int kb = kw + ((t + rot) & 15) * 64;
        char* lb = wbase + (t & 1) * 8192;
        #pragma unroll
        for (int i = 0; i < 8; ++i) {
            int r    = i * 4 + kg;           // row this lane's 16B lands in
            int blkg = rl ^ (r & 15);        // source block (inverse swizzle)
            const float* src = x + (size_t)(row0 + r) * DDIM + kb + blkg * 4;
            gload_lds16(src, lb + i * 1024);
        }
    };

    // B fragments for pipeline-step s (6 x 16B, L2-resident)
    auto loadB = [&](int s, bf16x8 (&bl)[6]) {
        const ushort* bp = w1b + (size_t)rl * DDIM + kw + ((s + rot) & 15) * 64 + kg * 8;
        #pragma unroll
        for (int n = 0; n < 3; ++n)
            #pragma unroll
            for (int h = 0; h < 2; ++h)
                bl[n * 2 + h] = *(const bf16x8*)(bp + n * 16 * DDIM + h * 32);
    };

    float ss0 = 0.f, ss1 = 0.f;
    f32x4 acc0[3] = {{0.f,0.f,0.f,0.f},{0.f,0.f,0.f,0.f},{0.f,0.f,0.f,0.f}};
    f32x4 acc1[3] = {{0.f,0.f,0.f,0.f},{0.f,0.f,0.f,0.f},{0.f,0.f,0.f,0.f}};
    bf16x8 bA[6], bB[6];

    // prologue: B0 issued BETWEEN the two stages so no wait ever drains stage(1)
    stage(0); loadB(0, bA); stage(1);

    auto body = [&](int s, bf16x8 (&bu)[6], bf16x8 (&bl)[6]) {
        // retire exactly stage(s): queue is [st(s):8][B(s):6][st(s+1):8]
        if (s == 0)       asm volatile("s_waitcnt vmcnt(14)" ::: "memory");
        else if (s == 15) asm volatile("s_waitcnt vmcnt(6)"  ::: "memory");
        else              asm volatile("s_waitcnt vmcnt(8)"  ::: "memory");
        char* lb = wbase + (s & 1) * 8192;
        f32x4 a[2][2][2];
        #pragma unroll
        for (int T = 0; T < 2; ++T)
            #pragma unroll
            for (int h = 0; h < 2; ++h)
                #pragma unroll
                for (int p = 0; p < 2; ++p)
                    a[T][h][p] = *(const f32x4*)(lb + dso[T][h][p]);
        if (s < 15) loadB(s + 1, bl);
        #pragma unroll
        for (int h = 0; h < 2; ++h) {
            f32x4 a0 = a[0][h][0], a1 = a[0][h][1];
            f32x4 c0 = a[1][h][0], c1 = a[1][h][1];
            ss0 = fmaf(a0.x, a0.x, ss0); ss0 = fmaf(a0.y, a0.y, ss0);
            ss0 = fmaf(a0.z, a0.z, ss0); ss0 = fmaf(a0.w, a0.w, ss0);
            ss0 = fmaf(a1.x, a1.x, ss0); ss0 = fmaf(a1.y, a1.y, ss0);
            ss0 = fmaf(a1.z, a1.z, ss0); ss0 = fmaf(a1.w, a1.w, ss0);
            ss1 = fmaf(c0.x, c0.x, ss1); ss1 = fmaf(c0.y, c0.y, ss1);
            ss1 = fmaf(c0.z, c0.z, ss1); ss1 = fmaf(c0.w, c0.w, ss1);
            ss1 = fmaf(c1.x, c1.x, ss1); ss1 = fmaf(c1.y, c1.y, ss1);
            ss1 = fmaf(c1.z, c1.z, ss1); ss1 = fmaf(c1.w, c1.w, ss1);
            union { bf16x8 v; unsigned u[4]; } af, ag;
            af.u[0] = cvt_pk(a0.x, a0.y); af.u[1] = cvt_pk(a0.z, a0.w);
            af.u[2] = cvt_pk(a1.x, a1.y); af.u[3] = cvt_pk(a1.z, a1.w);
            ag.u[0] = cvt_pk(c0.x, c0.y); ag.u[1] = cvt_pk(c0.z, c0.w);
            ag.u[2] = cvt_pk(c1.x, c1.y); ag.u[3] = cvt_pk(c1.z, c1.w);
            #pragma unroll
            for (int n = 0; n < 3; ++n) {
                acc0[n] = __builtin_amdgcn_mfma_f32_16x16x32_bf16(
                              af.v, bu[n * 2 + h], acc0[n], 0, 0, 0);
                acc1[n] = __builtin_amdgcn_mfma_f32_16x16x32_bf16(
                              ag.v, bu[n * 2 + h], acc1[n], 0, 0, 0);
            }
        }
        asm volatile("s_waitcnt lgkmcnt(0)" ::: "memory");
        if (s < 14) stage(s + 2);
    };

    for (int sp = 0; sp < 8; ++sp) {
        body(2 * sp,     bA, bB);
        body(2 * sp + 1, bB, bA);
    }

    ss0 += __shfl_xor(ss0, 16); ss0 += __shfl_xor(ss0, 32);
    ss1 += __shfl_xor(ss1, 16); ss1 += __shfl_xor(ss1, 32);
    if (lane < 16) { ssw[wave][lane] = ss0; ssw[wave][16 + lane] = ss1; }

    asm volatile("s_waitcnt vmcnt(0) lgkmcnt(0)" ::: "memory");
    __syncthreads();

    float* dots = (float*)smem;             // [4][32][48] = 24576 B
    float* gbuf = (float*)(smem + 24576);   // [32][48]    =  6144 B
    float* w2s  = (float*)(smem + 30720);   // [48][48]    =  9216 B

    #pragma unroll
    for (int n = 0; n < 3; ++n)
        #pragma unroll
        for (int i = 0; i < 4; ++i) {
            dots[(wave * 32 + kg * 4 + i) * 48 + n * 16 + rl]      = acc0[n][i];
            dots[(wave * 32 + 16 + kg * 4 + i) * 48 + n * 16 + rl] = acc1[n][i];
        }
    for (int i = tid; i < LTOT * LTOT; i += 256) w2s[i] = w2[i];
    if (tid < 32) {
        float st = ssw[0][tid] + ssw[1][tid] + ssw[2][tid] + ssw[3][tid];
        scl[tid] = rsqrtf(st * (1.0f / (float)DDIM) + 1e-5f);
    }
    __syncthreads();

    #pragma unroll
    for (int i = 0; i < 6; ++i) {
        int v = tid + i * 256;                 // 0..1535 = 32*48
        int row = v / 48, col = v - row * 48;
        float d = dots[(0 * 32 + row) * 48 + col] + dots[(1 * 32 + row) * 48 + col]
                + dots[(2 * 32 + row) * 48 + col] + dots[(3 * 32 + row) * 48 + col];
        float h = d * scl[row];
        gbuf[row * 48 + col] = h * 0.5f * (1.0f + erff(h * 0.70710678118654752f));
    }
    __syncthreads();

    #pragma unroll
    for (int i = 0; i < 6; ++i) {
        int v = tid + i * 256;
        int row = v / 48, l = v - row * 48;
        float sacc = 0.f;
        #pragma unroll
        for (int k = 0; k < LTOT; ++k)
            sacc = fmaf(gbuf[row * 48 + k], w2s[l * LTOT + k], sacc);
        int rg = row0 + row;
        int b  = rg >> 12;
        int t  = rg & 4095;
        int c  = l / 12, j = l - c * 12;
        out[(((size_t)(c * 4 + b) * 4096 + t) * 12) + j] = sacc;
    }
}

extern "C" void kernel_launch(void* const* d_in, const int* in_sizes, int n_in,
                              void* d_out, int out_size, void* d_ws, size_t ws_size,
                              hipStream_t stream) {
    const float* x  = (const float*)d_in[0];
    const float* W1 = (const float*)d_in[1];
    const float* W2 = (const float*)d_in[2];
    float* out = (float*)d_out;
    ushort* w1b = (ushort*)d_ws;

    w1cvt_kernel<<<(LTOT * DDIM) / 256, 256, 0, stream>>>(W1, w1b);
    fused_kernel<<<16384 / 32, 256, 0, stream>>>(x, w1b, W2, out);
}